// Round 2
// baseline (413.430 us; speedup 1.0000x reference)
//
#include <hip/hip_runtime.h>

// Problem constants (fixed by setup_inputs): B=1, H=16, N=4096, D=64, k=32
#define NTOK  4096
#define NHEAD 16
#define DHEAD 64
#define KSEL  32

// ---------------------------------------------------------------------------
// Kernel 1: exact top-32 per mask row, matching jax.lax.top_k tie semantics
// (larger value first; ties -> lower index). One 256-thread block per row.
// Row cached in LDS as an order-preserving u32 map of the float bits; each
// thread keeps a register local-max over its 16 strided positions; 32
// extract-max passes block-reduce the 256 register values; only the owner
// of the extracted position rescans its 16 slots.
// Packed compare key: (mapped_val << 12) | (NTOK-1-pos)  -> max key is the
// largest value, ties favor smaller pos. uniform(0,1) values are nonneg so
// mapped >= 0x80000000; cleared slots (0) can never win.
// ---------------------------------------------------------------------------
__global__ __launch_bounds__(256) void topk_kernel(const float* __restrict__ mask,
                                                   int* __restrict__ topk) {
    __shared__ unsigned int vals[NTOK];          // 16 KiB
    __shared__ unsigned long long red[4];
    const int n    = blockIdx.x;
    const int t    = threadIdx.x;
    const int lane = t & 63;
    const int wave = t >> 6;

    const float* row = mask + (size_t)n * NTOK;
    for (int i = t; i < NTOK; i += 256) {
        unsigned int f = __float_as_uint(row[i]);
        // total-order map: nonneg -> f | 0x80000000, neg -> ~f
        vals[i] = (f & 0x80000000u) ? ~f : (f | 0x80000000u);
    }
    __syncthreads();

    // register-resident local max over my 16 positions
    auto local_best = [&]() {
        unsigned long long b = 0ull;
        #pragma unroll
        for (int i = 0; i < NTOK / 256; ++i) {
            const int pos = i * 256 + t;
            const unsigned long long key =
                ((unsigned long long)vals[pos] << 12) | (unsigned int)(NTOK - 1 - pos);
            b = (key > b) ? key : b;
        }
        return b;
    };
    unsigned long long lbest = local_best();

    for (int sel = 0; sel < KSEL; ++sel) {
        // 64-lane wave reduction of register local-maxes
        unsigned long long best = lbest;
        #pragma unroll
        for (int off = 32; off > 0; off >>= 1) {
            unsigned long long o = __shfl_down(best, off, 64);
            best = (o > best) ? o : best;
        }
        if (lane == 0) red[wave] = best;
        __syncthreads();
        unsigned long long win = red[0];
        if (red[1] > win) win = red[1];
        if (red[2] > win) win = red[2];
        if (red[3] > win) win = red[3];
        const int pos = (NTOK - 1) - (int)(win & 0xFFFull);
        if (t == 0) topk[n * KSEL + sel] = pos;
        if (t == (pos & 255)) {          // owner rescans its 16 slots
            vals[pos] = 0u;
            lbest = local_best();
        }
        __syncthreads();                 // protect red[] before next pass
    }
}

// ---------------------------------------------------------------------------
// Kernel 2: per-(h,n) attention over the 32 selected neighbors.
// One 64-lane wave per (h,n); lane = d (head dim). Lanes 0..31 additionally
// hold the 32 neighbor indices / scores / softmax weights.
//   scores[j] = (1/8) * sum_d q[h,n,d] * key[h, idx[n,j], d]
//   out[h,n,d] = sum_j softmax(scores)[j] * value[h, idx[n,j], d]
// All K/V row loads are 64-lane x 4B = 256B coalesced; rows are L2/L3-hot.
// ---------------------------------------------------------------------------
__global__ __launch_bounds__(256) void attn_kernel(const float* __restrict__ q,
                                                   const float* __restrict__ key,
                                                   const float* __restrict__ val,
                                                   const int* __restrict__ topk,
                                                   float* __restrict__ out) {
    const int gwave = (int)((blockIdx.x * blockDim.x + threadIdx.x) >> 6);
    const int lane  = threadIdx.x & 63;
    const int h     = gwave >> 12;       // / NTOK
    const int n     = gwave & (NTOK - 1);

    int idxreg = 0;
    if (lane < KSEL) idxreg = topk[n * KSEL + lane];

    const float qd = q[((size_t)h * NTOK + n) * DHEAD + lane];
    const float* kh = key + (size_t)h * NTOK * DHEAD;
    const float* vh = val + (size_t)h * NTOK * DHEAD;

    // --- scores ---
    float s = 0.f;
    #pragma unroll 4
    for (int j = 0; j < KSEL; ++j) {
        const int ij = __shfl(idxreg, j, 64);
        float p = qd * kh[(size_t)ij * DHEAD + lane];
        #pragma unroll
        for (int off = 32; off > 0; off >>= 1) p += __shfl_xor(p, off, 64);
        if (lane == j) s = p;            // lane j keeps score j
    }
    s *= 0.125f;                          // 1/sqrt(64)

    // --- softmax over lanes 0..31 (width-32 segments; upper half unused) ---
    float sv = (lane < KSEL) ? s : -INFINITY;
    float m = sv;
    #pragma unroll
    for (int off = 16; off > 0; off >>= 1) m = fmaxf(m, __shfl_xor(m, off, 32));
    const float e = (lane < KSEL) ? __expf(sv - m) : 0.f;
    float sum = e;
    #pragma unroll
    for (int off = 16; off > 0; off >>= 1) sum += __shfl_xor(sum, off, 32);
    const float pc = e / sum;             // valid in lanes 0..31

    // --- weighted sum of V rows ---
    float acc = 0.f;
    #pragma unroll 4
    for (int j = 0; j < KSEL; ++j) {
        const int ij = __shfl(idxreg, j, 64);
        const float pj = __shfl(pc, j, 64);
        acc = fmaf(pj, vh[(size_t)ij * DHEAD + lane], acc);
    }
    out[((size_t)h * NTOK + n) * DHEAD + lane] = acc;
}

extern "C" void kernel_launch(void* const* d_in, const int* in_sizes, int n_in,
                              void* d_out, int out_size, void* d_ws, size_t ws_size,
                              hipStream_t stream) {
    const float* q    = (const float*)d_in[0];
    const float* k    = (const float*)d_in[1];
    const float* v    = (const float*)d_in[2];
    const float* mask = (const float*)d_in[3];
    // d_in[4] is k_nearest (==32), baked in as KSEL.

    int* topk = (int*)d_ws;               // NTOK*KSEL*4 = 512 KiB scratch

    topk_kernel<<<NTOK, 256, 0, stream>>>(mask, topk);

    const int total_waves = NHEAD * NTOK;                 // 65536
    const int blocks = total_waves * 64 / 256;            // 16384
    attn_kernel<<<blocks, 256, 0, stream>>>(q, k, v, topk, (float*)d_out);
}

// Round 3
// 195.061 us; speedup vs baseline: 2.1195x; 2.1195x over previous
//
#include <hip/hip_runtime.h>

// Problem constants (fixed by setup_inputs): B=1, H=16, N=4096, D=64, k=32
#define NTOK  4096
#define NHEAD 16
#define DHEAD 64
#define KSEL  32
#define CAND_CAP 256

typedef unsigned long long u64;
typedef unsigned int u32;

// order-preserving map of float bits (handles negatives for safety; mask is [0,1))
__device__ __forceinline__ u32 order_map(float f) {
    u32 b = __float_as_uint(f);
    return (b & 0x80000000u) ? ~b : (b | 0x80000000u);
}

// ---------------------------------------------------------------------------
// Kernel 1: top-32 SET per mask row (output order irrelevant: both einsums
// contract over k, softmax is permutation-equivariant). Histogram select:
//   - 256-bin histogram on floor(f*256) (monotone partition of the value axis;
//     uniform data -> ~16/bin, no atomic hot-spotting)
//   - serial suffix scan (expected ~3 iters) finds boundary bin b*
//   - bins > b*: definitely in top-32 -> append unordered via LDS slot counter
//   - bin == b*: candidates (expected ~16) -> exact top-(32-above) extraction
//     with packed u64 key (mapped_val<<12 | 4095-pos) matching jax.lax.top_k
//     tie rules (value desc, index asc). Keys unique -> clean owner-clear.
// 3 barriers total (vs 64 in the old 32-pass design).
// ---------------------------------------------------------------------------
__global__ __launch_bounds__(256) void topk_kernel(const float* __restrict__ mask,
                                                   int* __restrict__ topk) {
    __shared__ u32 hist[256];
    __shared__ u64 cand[CAND_CAP];
    __shared__ int sh_bstar, sh_above, sh_cand_cnt, sh_def_cnt;
    const int n = blockIdx.x;
    const int t = threadIdx.x;

    hist[t] = 0;
    if (t == 0) { sh_cand_cnt = 0; sh_def_cnt = 0; }
    __syncthreads();

    const float* row = mask + (size_t)n * NTOK;
    float f[16];
    #pragma unroll
    for (int k = 0; k < 4; ++k) {
        float4 v = *reinterpret_cast<const float4*>(row + k * 1024 + t * 4);
        f[k * 4 + 0] = v.x; f[k * 4 + 1] = v.y;
        f[k * 4 + 2] = v.z; f[k * 4 + 3] = v.w;
    }
    #pragma unroll
    for (int e = 0; e < 16; ++e) {
        int b = (int)(f[e] * 256.0f);
        b = b < 0 ? 0 : (b > 255 ? 255 : b);
        atomicAdd(&hist[b], 1u);
    }
    __syncthreads();

    if (t == 0) {
        int s = 0, b = 255;
        while (b >= 0) { s += (int)hist[b]; if (s >= KSEL) break; --b; }
        sh_bstar = b;
        sh_above = s - (int)hist[b];   // strictly-above count, < 32 by construction
    }
    __syncthreads();
    const int bstar = sh_bstar;
    const int above = sh_above;

    #pragma unroll
    for (int e = 0; e < 16; ++e) {
        int b = (int)(f[e] * 256.0f);
        b = b < 0 ? 0 : (b > 255 ? 255 : b);
        const int pos = (e >> 2) * 1024 + t * 4 + (e & 3);
        if (b > bstar) {
            int slot = atomicAdd(&sh_def_cnt, 1);
            topk[n * KSEL + slot] = pos;            // unordered append: fine
        } else if (b == bstar) {
            int slot = atomicAdd(&sh_cand_cnt, 1);
            if (slot < CAND_CAP)
                cand[slot] = ((u64)order_map(f[e]) << 12) | (u32)(NTOK - 1 - pos);
        }
    }
    __syncthreads();

    // exact extraction of the remaining (32-above) from boundary candidates
    if (t < 64) {
        const int lane = t;
        const int cnt = sh_cand_cnt < CAND_CAP ? sh_cand_cnt : CAND_CAP;
        u64 k0 = (lane       < cnt) ? cand[lane]       : 0ull;
        u64 k1 = (lane + 64  < cnt) ? cand[lane + 64]  : 0ull;
        u64 k2 = (lane + 128 < cnt) ? cand[lane + 128] : 0ull;
        u64 k3 = (lane + 192 < cnt) ? cand[lane + 192] : 0ull;
        const int r = KSEL - above;
        for (int sel = 0; sel < r; ++sel) {
            u64 m01 = k0 > k1 ? k0 : k1;
            u64 m23 = k2 > k3 ? k2 : k3;
            u64 m   = m01 > m23 ? m01 : m23;
            #pragma unroll
            for (int off = 1; off <= 32; off <<= 1) {
                u64 o = __shfl_xor(m, off, 64);
                m = o > m ? o : m;
            }
            if (lane == 0)
                topk[n * KSEL + above + sel] = (NTOK - 1) - (int)(m & 0xFFFull);
            k0 = (k0 == m) ? 0ull : k0;
            k1 = (k1 == m) ? 0ull : k1;
            k2 = (k2 == m) ? 0ull : k2;
            k3 = (k3 == m) ? 0ull : k3;
        }
    }
}

// ---------------------------------------------------------------------------
// Kernel 2: per-(h,n) attention, 4-rows-per-wave layout.
// lane = 16*r + c: group r handles neighbor rows j = 4i+r, chunk c covers
// d = 4c..4c+3. One float4 load per lane covers 4 K/V rows per wave-instr
// (1 KiB, fully coalesced in 4x256B segments). Score reduce: 4 shfl_xor over
// the 16-lane group; softmax in registers (2 cross-group shuffles).
// h = blockIdx & 15 pins heads {x, x+8} to XCD x (blockIdx % 8 == XCD):
// K+V working set per XCD = 4 MB ~= L2-resident.
// ---------------------------------------------------------------------------
__global__ __launch_bounds__(256) void attn_kernel(const float* __restrict__ q,
                                                   const float* __restrict__ key,
                                                   const float* __restrict__ val,
                                                   const int* __restrict__ topk,
                                                   float* __restrict__ out) {
    const int blk  = blockIdx.x;
    const int h    = blk & (NHEAD - 1);
    const int wave = threadIdx.x >> 6;
    const int lane = threadIdx.x & 63;
    const int n    = ((blk >> 4) << 2) | wave;
    const int r    = lane >> 4;
    const int c    = lane & 15;

    const int idxreg = topk[n * KSEL + (lane & 31)];
    const float* kh = key + (size_t)h * NTOK * DHEAD;
    const float* vh = val + (size_t)h * NTOK * DHEAD;
    const size_t qoff = ((size_t)h * NTOK + n) * DHEAD;

    const float4 qf = *reinterpret_cast<const float4*>(q + qoff + c * 4);

    int   ij[8];
    float s[8];
    #pragma unroll
    for (int i = 0; i < 8; ++i) {
        ij[i] = __shfl(idxreg, 4 * i + r, 64);
        const float4 kf = *reinterpret_cast<const float4*>(kh + (size_t)ij[i] * DHEAD + c * 4);
        float p = qf.x * kf.x;
        p = fmaf(qf.y, kf.y, p);
        p = fmaf(qf.z, kf.z, p);
        p = fmaf(qf.w, kf.w, p);
        p += __shfl_xor(p, 1, 64);
        p += __shfl_xor(p, 2, 64);
        p += __shfl_xor(p, 4, 64);
        p += __shfl_xor(p, 8, 64);
        s[i] = p * 0.125f;                  // 1/sqrt(64)
    }

    // softmax over all 32 scores; each lane holds the 8 of its group r
    float m = s[0];
    #pragma unroll
    for (int i = 1; i < 8; ++i) m = fmaxf(m, s[i]);
    m = fmaxf(m, __shfl_xor(m, 16, 64));
    m = fmaxf(m, __shfl_xor(m, 32, 64));
    float sum = 0.f;
    #pragma unroll
    for (int i = 0; i < 8; ++i) { s[i] = __expf(s[i] - m); sum += s[i]; }
    sum += __shfl_xor(sum, 16, 64);
    sum += __shfl_xor(sum, 32, 64);
    const float inv = 1.0f / sum;

    float ax = 0.f, ay = 0.f, az = 0.f, aw = 0.f;
    #pragma unroll
    for (int i = 0; i < 8; ++i) {
        const float4 vf = *reinterpret_cast<const float4*>(vh + (size_t)ij[i] * DHEAD + c * 4);
        const float w = s[i] * inv;
        ax = fmaf(w, vf.x, ax);
        ay = fmaf(w, vf.y, ay);
        az = fmaf(w, vf.z, az);
        aw = fmaf(w, vf.w, aw);
    }
    // reduce across the 4 row-groups (lanes c, 16+c, 32+c, 48+c)
    ax += __shfl_xor(ax, 16, 64); ax += __shfl_xor(ax, 32, 64);
    ay += __shfl_xor(ay, 16, 64); ay += __shfl_xor(ay, 32, 64);
    az += __shfl_xor(az, 16, 64); az += __shfl_xor(az, 32, 64);
    aw += __shfl_xor(aw, 16, 64); aw += __shfl_xor(aw, 32, 64);

    if (lane < 16) {
        float4 o; o.x = ax; o.y = ay; o.z = az; o.w = aw;
        *reinterpret_cast<float4*>(out + qoff + lane * 4) = o;
    }
}

extern "C" void kernel_launch(void* const* d_in, const int* in_sizes, int n_in,
                              void* d_out, int out_size, void* d_ws, size_t ws_size,
                              hipStream_t stream) {
    const float* q    = (const float*)d_in[0];
    const float* k    = (const float*)d_in[1];
    const float* v    = (const float*)d_in[2];
    const float* mask = (const float*)d_in[3];
    // d_in[4] is k_nearest (==32), baked in as KSEL.

    int* topk = (int*)d_ws;               // NTOK*KSEL*4 = 512 KiB scratch

    topk_kernel<<<NTOK, 256, 0, stream>>>(mask, topk);

    // 65536 (h,n) waves, 4 waves/block, h = blk & 15 for XCD affinity
    attn_kernel<<<NHEAD * NTOK / 4, 256, 0, stream>>>(q, k, v, topk, (float*)d_out);
}